// Round 16
// baseline (31.387 us; speedup 1.0000x reference)
//
#include <hip/hip_runtime.h>

constexpr int B = 64, N = 8732, C = 21, M = 16;
constexpr int TROW = 1 + 6 * M;       // 97
constexpr int NBIN = 2048;            // windowed bins (2 float16-key steps wide)
constexpr unsigned BASE16 = 15103u;   // key16 window start
constexpr int NSLAB = 8;
constexpr int TILE = 128;             // rows per tile
constexpr int NTILES = (N + TILE - 1) / TILE;  // 69 (last tile = 28 rows)
constexpr int BPB = 16;               // blocks per batch -> grid 16x64 = 1024 = 4/CU
constexpr float FSCALE = 262144.0f;   // 2^18 fixed-point for CE sums
constexpr unsigned long long CNT1 = 1ull << 44;
constexpr unsigned long long FIXMASK = (1ull << 44) - 1;

__device__ __forceinline__ unsigned f2key(float f) {
  unsigned u = __float_as_uint(f);
  return (u & 0x80000000u) ? ~u : (u | 0x80000000u);
}
__device__ __forceinline__ float key2f(unsigned k) {
  unsigned u = (k & 0x80000000u) ? (k ^ 0x80000000u) : ~k;
  return __uint_as_float(u);
}

// ---- zero the slabs (8 * 2048 u64 = 128 KB) ----
__global__ __launch_bounds__(256) void k_zero(unsigned long long* __restrict__ z) {
  int idx = blockIdx.x * 256 + threadIdx.x;   // 64 blocks * 256
  z[idx] = 0ull;
}

// ---- logp: double-buffered reg->LDS pipeline, 128-row tiles, 4 blocks/CU ----
__global__ __launch_bounds__(256) void k_logp(
    const float* __restrict__ conf, const float* __restrict__ bbox,
    const float* __restrict__ target, const float* __restrict__ pred,
    unsigned long long* __restrict__ slab1, float4* __restrict__ batchCtl) {
  __shared__ __align__(16) float sbuf[2][TILE * C];    // 21504 B
  __shared__ unsigned long long shist[NBIN];           // 16384 B
  __shared__ int sk[M];
  int b = blockIdx.y, bx = blockIdx.x, tid = threadIdx.x;

  for (int i = tid; i < NBIN; i += 256) shist[i] = 0ull;
  const float* tr = target + (size_t)b * TROW;
  if (tid < M) {
    int num = (int)tr[0];
    sk[tid] = (tid < num) ? (int)tr[1 + 6 * tid + 5] : -1;
  }

  const size_t cbase = (size_t)b * N;
  int nt = (NTILES - 1 - bx) / BPB + 1;

  uint4 r0, r1, r2;
  int ld_nf4 = 0;

#define LOAD_T(kt)                                                        \
  {                                                                       \
    int tt_ = bx + (kt) * BPB;                                            \
    int n0_ = tt_ * TILE;                                                 \
    int rows_ = min(TILE, N - n0_);                                       \
    ld_nf4 = (rows_ * C) >> 2;                                            \
    const uint4* g4_ = (const uint4*)(conf + (cbase + n0_) * C);          \
    if (tid < ld_nf4) r0 = g4_[tid];                                      \
    if (tid + 256 < ld_nf4) r1 = g4_[tid + 256];                          \
    if (tid + 512 < ld_nf4) r2 = g4_[tid + 512];                          \
  }

#define WRITE_T(bi)                                                       \
  {                                                                       \
    uint4* s4_ = (uint4*)sbuf[bi];                                        \
    if (tid < ld_nf4) s4_[tid] = r0;                                      \
    if (tid + 256 < ld_nf4) s4_[tid + 256] = r1;                          \
    if (tid + 512 < ld_nf4) s4_[tid + 512] = r2;                          \
  }

  LOAD_T(0);
  WRITE_T(0);
  __syncthreads();

  for (int t = 0; t < nt; ++t) {
    if (t + 1 < nt) LOAD_T(t + 1);     // fire next-tile loads before compute
    {
      int tt_ = bx + t * BPB;
      int n0_ = tt_ * TILE;
      int rows_ = min(TILE, N - n0_);
      if (tid < rows_) {
        int n = n0_ + tid;
        const float* x = sbuf[t & 1] + tid * C;
        float s0 = __expf(x[0]) + __expf(x[4]) + __expf(x[8]) + __expf(x[12]) + __expf(x[16]);
        float s1 = __expf(x[1]) + __expf(x[5]) + __expf(x[9]) + __expf(x[13]) + __expf(x[17]);
        float s2 = __expf(x[2]) + __expf(x[6]) + __expf(x[10]) + __expf(x[14]) + __expf(x[18]);
        float s3 = __expf(x[3]) + __expf(x[7]) + __expf(x[11]) + __expf(x[15]) + __expf(x[19]);
        float s = (s0 + s1) + (s2 + s3) + __expf(x[20]);
        float lp = x[0] - __logf(s);
        bool asg = false;
        for (int j = 0; j < M; j++) asg |= (sk[j] == n);
        if (!asg) {
          int idx = ((int)(f2key(lp) >> 16) - (int)BASE16) >> 1;
          idx = min(max(idx, 0), NBIN - 1);
          atomicAdd(&shist[idx],
                    CNT1 | (unsigned long long)((-lp) * FSCALE + 0.5f));
        }
      }
    }
    if (t + 1 < nt) WRITE_T((t + 1) & 1);
    __syncthreads();
  }
#undef LOAD_T
#undef WRITE_T

  unsigned long long* sg = slab1 + (size_t)(bx & (NSLAB - 1)) * NBIN;
  for (int i = tid; i < NBIN; i += 256) {
    unsigned long long v = shist[i];
    if (v) atomicAdd(&sg[i], v);
  }

  if (bx == 0) {
    float myValid = 0.f, myPos = 0.f, myCE = 0.f, mySL = 0.f;
    if (tid < M && sk[tid] >= 0) {
      const float* e = tr + 1 + 6 * tid;
      int cls = (int)e[0];
      float tx1 = e[1], ty1 = e[2], tx2 = e[3], ty2 = e[4];
      int k = sk[tid];
      float p0 = pred[k * 4 + 0], p1 = pred[k * 4 + 1];
      float p2 = pred[k * 4 + 2], p3 = pred[k * 4 + 3];
      float pw = p2 - p0, ph = p3 - p1;
      float pcx = (p0 + p2) * 0.5f, pcy = (p1 + p3) * 0.5f;
      float tw = tx2 - tx1, th = ty2 - ty1;
      float tcx = (tx1 + tx2) * 0.5f, tcy = (ty1 + ty2) * 0.5f;
      float ebv[4];
      ebv[0] = (tcx - pcx) / pw;
      ebv[1] = (tcy - pcy) / ph;
      ebv[2] = __logf(tw / pw);
      ebv[3] = __logf(th / ph);
      const float* bo = bbox + ((size_t)b * N + k) * 4;
      float sl = 0.f;
      for (int j = 0; j < 4; j++) {
        float d = bo[j] - ebv[j];
        float ad = fabsf(d);
        sl += (ad < 1.f) ? 0.5f * d * d : ad - 0.5f;
      }
      myValid = 1.f; mySL = sl;
      if (cls > 0) {
        const float* x = conf + ((size_t)b * N + k) * C;
        float s = 0.f;
        for (int c = 0; c < C; c++) s += __expf(x[c]);
        float lp = x[cls] - __logf(s);
        myPos = 1.f; myCE = -lp;
      }
    }
    if (tid < 64) {
      for (int off = 32; off; off >>= 1) {
        myValid += __shfl_down(myValid, off, 64);
        myPos   += __shfl_down(myPos, off, 64);
        myCE    += __shfl_down(myCE, off, 64);
        mySL    += __shfl_down(mySL, off, 64);
      }
      if (tid == 0) batchCtl[b] = make_float4(myPos, myValid, myCE, mySL);
    }
  }
}

// ---- fin: reduce slabs + scan + interpolate + outputs (1 block, 1024 thr) ----
__global__ __launch_bounds__(1024) void k_fin(
    const unsigned long long* __restrict__ slab1,
    const float4* __restrict__ batchCtl, float* __restrict__ out) {
  __shared__ unsigned long long sm[NBIN];      // 16 KB
  __shared__ unsigned long long sscan[1024];   // 8 KB
  __shared__ unsigned srank;
  __shared__ float sp, sva, sce, ssl;
  __shared__ double sNeg;
  int tid = threadIdx.x;

  if (tid < 64) {
    float4 v = batchCtl[tid];
    float p = v.x, va = v.y, ce = v.z, sl = v.w;
    for (int off = 32; off; off >>= 1) {
      p  += __shfl_down(p, off, 64);
      va += __shfl_down(va, off, 64);
      ce += __shfl_down(ce, off, 64);
      sl += __shfl_down(sl, off, 64);
    }
    if (tid == 0) {
      sp = p; sva = va; sce = ce; ssl = sl;
      srank = 3u * (unsigned)(p + 0.5f);
      sNeg = 0.0;
    }
  }

  for (int k = 0; k < NBIN / 1024; k++) {
    int bin = tid + k * 1024;
    unsigned long long v = 0ull;
    for (int s = 0; s < NSLAB; s++) v += slab1[(size_t)s * NBIN + bin];
    sm[bin] = v;
  }
  __syncthreads();

  unsigned long long h2[2];
  unsigned long long part = 0ull;
  for (int j = 0; j < 2; j++) { h2[j] = sm[tid * 2 + j]; part += h2[j]; }
  sscan[tid] = part;
  __syncthreads();
  for (int off = 1; off < 1024; off <<= 1) {
    unsigned long long add = (tid >= off) ? sscan[tid - off] : 0ull;
    __syncthreads();
    sscan[tid] += add;
    __syncthreads();
  }

  unsigned rank = srank;
  if (rank) {
    unsigned long long cum = sscan[tid] - part;
    for (int j = 0; j < 2; j++) {
      unsigned long long h = h2[j];
      unsigned c0 = (unsigned)(cum >> 44);
      unsigned c1 = (unsigned)((cum + h) >> 44);
      if (c0 < rank && c1 >= rank) {
        unsigned t = (unsigned)(tid * 2 + j);
        unsigned r = rank - c0;
        unsigned long long fixBelow = cum & FIXMASK;
        float ceEdge = -key2f((BASE16 + 2u * t) << 16);
        sNeg = (double)fixBelow / 262144.0 + (double)r * (double)ceEdge;
      }
      cum += h;
    }
  }
  __syncthreads();
  if (tid == 0) {
    out[0] = (sce + (float)sNeg) / fmaxf(4.0f * sp, 1.0f);
    out[1] = ssl / fmaxf(4.0f * sva, 1.0f);
  }
}

extern "C" void kernel_launch(void* const* d_in, const int* in_sizes, int n_in,
                              void* d_out, int out_size, void* d_ws, size_t ws_size,
                              hipStream_t stream) {
  const float* conf = (const float*)d_in[0];
  const float* bbox = (const float*)d_in[1];
  const float* target = (const float*)d_in[2];
  const float* pred = (const float*)d_in[3];
  float* out = (float*)d_out;

  char* ws = (char*)d_ws;
  unsigned long long* slab1 = (unsigned long long*)ws;
  size_t off = (size_t)NSLAB * NBIN * 8;                // 128 KB
  float4* batchCtl = (float4*)(ws + off); off += 64 * 16;

  k_zero<<<64, 256, 0, stream>>>(slab1);
  k_logp<<<dim3(BPB, B), 256, 0, stream>>>(conf, bbox, target, pred,
                                           slab1, batchCtl);
  k_fin<<<1, 1024, 0, stream>>>(slab1, batchCtl, out);
}

// Round 17
// 28.420 us; speedup vs baseline: 1.1044x; 1.1044x over previous
//
#include <hip/hip_runtime.h>

constexpr int B = 64, N = 8732, C = 21, M = 16;
constexpr int TROW = 1 + 6 * M;       // 97
constexpr int NBIN = 2048;            // windowed bins (2 float16-key steps wide)
constexpr unsigned BASE16 = 15103u;   // key16 window start
constexpr int NSLAB = 8;
constexpr int TILE = 256;             // rows per tile
constexpr int NTILES = (N + TILE - 1) / TILE;  // 35 (last tile = 28 rows)
constexpr int BPB = 8;                // blocks per batch -> grid 8x64 = 512 = 2/CU
constexpr float FSCALE = 262144.0f;   // 2^18 fixed-point for CE sums
constexpr unsigned long long CNT1 = 1ull << 44;
constexpr unsigned long long FIXMASK = (1ull << 44) - 1;

__device__ __forceinline__ unsigned f2key(float f) {
  unsigned u = __float_as_uint(f);
  return (u & 0x80000000u) ? ~u : (u | 0x80000000u);
}
__device__ __forceinline__ float key2f(unsigned k) {
  unsigned u = (k & 0x80000000u) ? (k ^ 0x80000000u) : ~k;
  return __uint_as_float(u);
}

// ---- zero the slabs (8 * 2048 u64 = 128 KB) ----
__global__ __launch_bounds__(256) void k_zero(unsigned long long* __restrict__ z) {
  int idx = blockIdx.x * 256 + threadIdx.x;   // 64 blocks * 256
  z[idx] = 0ull;
}

// ---- logp: 2-tile-deep register prefetch + double-buffered LDS.
// ---- Loads for tile t+2 are issued at iter t (2 compute windows of slack;
// ---- reg loads aren't drained by __syncthreads - only their ds_write use). ----
__global__ __launch_bounds__(256) void k_logp(
    const float* __restrict__ conf, const float* __restrict__ bbox,
    const float* __restrict__ target, const float* __restrict__ pred,
    unsigned long long* __restrict__ slab1, float4* __restrict__ batchCtl) {
  __shared__ __align__(16) float sbuf[2][TILE * C];    // 43008 B
  __shared__ unsigned long long shist[NBIN];           // 16384 B
  __shared__ int sk[M];
  int b = blockIdx.y, bx = blockIdx.x, tid = threadIdx.x;

  for (int i = tid; i < NBIN; i += 256) shist[i] = 0ull;
  const float* tr = target + (size_t)b * TROW;
  if (tid < M) {
    int num = (int)tr[0];
    sk[tid] = (tid < num) ? (int)tr[1 + 6 * tid + 5] : -1;
  }

  const size_t cbase = (size_t)b * N;
  int nt = (NTILES - 1 - bx) / BPB + 1;   // 5 for bx<3, else 4

  uint4 a0, a1, a2, a3, a4, a5;   // prefetch set A
  uint4 b0, b1, b2, b3, b4, b5;   // prefetch set B
  int la = 0, lb = 0;

#define LOAD_SET(R0, R1, R2, R3, R4, R5, LN, kt)                          \
  {                                                                       \
    int tt_ = bx + (kt) * BPB;                                            \
    int n0_ = tt_ * TILE;                                                 \
    int rows_ = min(TILE, N - n0_);                                       \
    LN = (rows_ * C) >> 2;                                                \
    const uint4* g4_ = (const uint4*)(conf + (cbase + n0_) * C);          \
    if (tid < LN) R0 = g4_[tid];                                          \
    if (tid + 256 < LN) R1 = g4_[tid + 256];                              \
    if (tid + 512 < LN) R2 = g4_[tid + 512];                              \
    if (tid + 768 < LN) R3 = g4_[tid + 768];                              \
    if (tid + 1024 < LN) R4 = g4_[tid + 1024];                            \
    if (tid + 1280 < LN) R5 = g4_[tid + 1280];                            \
  }

#define WRITE_SET(R0, R1, R2, R3, R4, R5, LN, bi)                         \
  {                                                                       \
    uint4* s4_ = (uint4*)sbuf[bi];                                        \
    if (tid < LN) s4_[tid] = R0;                                          \
    if (tid + 256 < LN) s4_[tid + 256] = R1;                              \
    if (tid + 512 < LN) s4_[tid + 512] = R2;                              \
    if (tid + 768 < LN) s4_[tid + 768] = R3;                              \
    if (tid + 1024 < LN) s4_[tid + 1024] = R4;                            \
    if (tid + 1280 < LN) s4_[tid + 1280] = R5;                            \
  }

  // prologue: tile0 -> A -> buf0; tile1 -> B (written at end of iter 0)
  LOAD_SET(a0, a1, a2, a3, a4, a5, la, 0);
  WRITE_SET(a0, a1, a2, a3, a4, a5, la, 0);
  if (1 < nt) LOAD_SET(b0, b1, b2, b3, b4, b5, lb, 1);
  __syncthreads();

  for (int t = 0; t < nt; ++t) {
    // issue tile t+2 into the set freed at the previous iteration's write
    if (t + 2 < nt) {
      if ((t & 1) == 0) { LOAD_SET(a0, a1, a2, a3, a4, a5, la, t + 2); }
      else              { LOAD_SET(b0, b1, b2, b3, b4, b5, lb, t + 2); }
    }
    {
      int tt_ = bx + t * BPB;
      int n0_ = tt_ * TILE;
      int rows_ = min(TILE, N - n0_);
      if (tid < rows_) {
        int n = n0_ + tid;
        const float* x = sbuf[t & 1] + tid * C;
        float s0 = __expf(x[0]) + __expf(x[4]) + __expf(x[8]) + __expf(x[12]) + __expf(x[16]);
        float s1 = __expf(x[1]) + __expf(x[5]) + __expf(x[9]) + __expf(x[13]) + __expf(x[17]);
        float s2 = __expf(x[2]) + __expf(x[6]) + __expf(x[10]) + __expf(x[14]) + __expf(x[18]);
        float s3 = __expf(x[3]) + __expf(x[7]) + __expf(x[11]) + __expf(x[15]) + __expf(x[19]);
        float s = (s0 + s1) + (s2 + s3) + __expf(x[20]);
        float lp = x[0] - __logf(s);
        bool asg = false;
        for (int j = 0; j < M; j++) asg |= (sk[j] == n);
        if (!asg) {
          int idx = ((int)(f2key(lp) >> 16) - (int)BASE16) >> 1;
          idx = min(max(idx, 0), NBIN - 1);
          atomicAdd(&shist[idx],
                    CNT1 | (unsigned long long)((-lp) * FSCALE + 0.5f));
        }
      }
    }
    // write tile t+1 (held in set[(t+1)&1]) into buf[(t+1)&1]
    if (t + 1 < nt) {
      if (((t + 1) & 1) == 0) { WRITE_SET(a0, a1, a2, a3, a4, a5, la, 0); }
      else                    { WRITE_SET(b0, b1, b2, b3, b4, b5, lb, 1); }
    }
    __syncthreads();
  }
#undef LOAD_SET
#undef WRITE_SET

  unsigned long long* sg = slab1 + (size_t)(bx & (NSLAB - 1)) * NBIN;
  for (int i = tid; i < NBIN; i += 256) {
    unsigned long long v = shist[i];
    if (v) atomicAdd(&sg[i], v);
  }

  if (bx == 0) {
    float myValid = 0.f, myPos = 0.f, myCE = 0.f, mySL = 0.f;
    if (tid < M && sk[tid] >= 0) {
      const float* e = tr + 1 + 6 * tid;
      int cls = (int)e[0];
      float tx1 = e[1], ty1 = e[2], tx2 = e[3], ty2 = e[4];
      int k = sk[tid];
      float p0 = pred[k * 4 + 0], p1 = pred[k * 4 + 1];
      float p2 = pred[k * 4 + 2], p3 = pred[k * 4 + 3];
      float pw = p2 - p0, ph = p3 - p1;
      float pcx = (p0 + p2) * 0.5f, pcy = (p1 + p3) * 0.5f;
      float tw = tx2 - tx1, th = ty2 - ty1;
      float tcx = (tx1 + tx2) * 0.5f, tcy = (ty1 + ty2) * 0.5f;
      float ebv[4];
      ebv[0] = (tcx - pcx) / pw;
      ebv[1] = (tcy - pcy) / ph;
      ebv[2] = __logf(tw / pw);
      ebv[3] = __logf(th / ph);
      const float* bo = bbox + ((size_t)b * N + k) * 4;
      float sl = 0.f;
      for (int j = 0; j < 4; j++) {
        float d = bo[j] - ebv[j];
        float ad = fabsf(d);
        sl += (ad < 1.f) ? 0.5f * d * d : ad - 0.5f;
      }
      myValid = 1.f; mySL = sl;
      if (cls > 0) {
        const float* x = conf + ((size_t)b * N + k) * C;
        float s = 0.f;
        for (int c = 0; c < C; c++) s += __expf(x[c]);
        float lp = x[cls] - __logf(s);
        myPos = 1.f; myCE = -lp;
      }
    }
    if (tid < 64) {
      for (int off = 32; off; off >>= 1) {
        myValid += __shfl_down(myValid, off, 64);
        myPos   += __shfl_down(myPos, off, 64);
        myCE    += __shfl_down(myCE, off, 64);
        mySL    += __shfl_down(mySL, off, 64);
      }
      if (tid == 0) batchCtl[b] = make_float4(myPos, myValid, myCE, mySL);
    }
  }
}

// ---- fin: reduce slabs + scan + interpolate + outputs (1 block, 1024 thr) ----
__global__ __launch_bounds__(1024) void k_fin(
    const unsigned long long* __restrict__ slab1,
    const float4* __restrict__ batchCtl, float* __restrict__ out) {
  __shared__ unsigned long long sm[NBIN];      // 16 KB
  __shared__ unsigned long long sscan[1024];   // 8 KB
  __shared__ unsigned srank;
  __shared__ float sp, sva, sce, ssl;
  __shared__ double sNeg;
  int tid = threadIdx.x;

  if (tid < 64) {
    float4 v = batchCtl[tid];
    float p = v.x, va = v.y, ce = v.z, sl = v.w;
    for (int off = 32; off; off >>= 1) {
      p  += __shfl_down(p, off, 64);
      va += __shfl_down(va, off, 64);
      ce += __shfl_down(ce, off, 64);
      sl += __shfl_down(sl, off, 64);
    }
    if (tid == 0) {
      sp = p; sva = va; sce = ce; ssl = sl;
      srank = 3u * (unsigned)(p + 0.5f);
      sNeg = 0.0;
    }
  }

  for (int k = 0; k < NBIN / 1024; k++) {
    int bin = tid + k * 1024;
    unsigned long long v = 0ull;
    for (int s = 0; s < NSLAB; s++) v += slab1[(size_t)s * NBIN + bin];
    sm[bin] = v;
  }
  __syncthreads();

  unsigned long long h2[2];
  unsigned long long part = 0ull;
  for (int j = 0; j < 2; j++) { h2[j] = sm[tid * 2 + j]; part += h2[j]; }
  sscan[tid] = part;
  __syncthreads();
  for (int off = 1; off < 1024; off <<= 1) {
    unsigned long long add = (tid >= off) ? sscan[tid - off] : 0ull;
    __syncthreads();
    sscan[tid] += add;
    __syncthreads();
  }

  unsigned rank = srank;
  if (rank) {
    unsigned long long cum = sscan[tid] - part;
    for (int j = 0; j < 2; j++) {
      unsigned long long h = h2[j];
      unsigned c0 = (unsigned)(cum >> 44);
      unsigned c1 = (unsigned)((cum + h) >> 44);
      if (c0 < rank && c1 >= rank) {
        unsigned t = (unsigned)(tid * 2 + j);
        unsigned r = rank - c0;
        unsigned long long fixBelow = cum & FIXMASK;
        float ceEdge = -key2f((BASE16 + 2u * t) << 16);
        sNeg = (double)fixBelow / 262144.0 + (double)r * (double)ceEdge;
      }
      cum += h;
    }
  }
  __syncthreads();
  if (tid == 0) {
    out[0] = (sce + (float)sNeg) / fmaxf(4.0f * sp, 1.0f);
    out[1] = ssl / fmaxf(4.0f * sva, 1.0f);
  }
}

extern "C" void kernel_launch(void* const* d_in, const int* in_sizes, int n_in,
                              void* d_out, int out_size, void* d_ws, size_t ws_size,
                              hipStream_t stream) {
  const float* conf = (const float*)d_in[0];
  const float* bbox = (const float*)d_in[1];
  const float* target = (const float*)d_in[2];
  const float* pred = (const float*)d_in[3];
  float* out = (float*)d_out;

  char* ws = (char*)d_ws;
  unsigned long long* slab1 = (unsigned long long*)ws;
  size_t off = (size_t)NSLAB * NBIN * 8;                // 128 KB
  float4* batchCtl = (float4*)(ws + off); off += 64 * 16;

  k_zero<<<64, 256, 0, stream>>>(slab1);
  k_logp<<<dim3(BPB, B), 256, 0, stream>>>(conf, bbox, target, pred,
                                           slab1, batchCtl);
  k_fin<<<1, 1024, 0, stream>>>(slab1, batchCtl, out);
}